// Round 11
// baseline (251.035 us; speedup 1.0000x reference)
//
#include <hip/hip_runtime.h>
#include <math.h>

typedef _Float16 f16x8 __attribute__((ext_vector_type(8)));
typedef float f32x4 __attribute__((ext_vector_type(4)));

// Problem constants
#define NROWS 32768   // 8*4096 input rows
#define KEMB  8192    // codebook entries
// DIM = 64

#define DECAYF 0.99f
#define OMDF   0.01f

// d_out layout (floats), reference return order
#define OUT_Q    0          // quantized, 2097152
#define OUT_LOSS 2097152    // vq_loss, 1
#define OUT_IDX  2097153    // idx (as float), 32768
#define OUT_PERP 2129921    // perplexity, 1
#define OUT_NW   2129922    // new_weight, 524288
#define OUT_NCC  2654210    // new_cc, 8192
#define OUT_NWS  2662402    // new_ws, 524288

// d_ws layout (4-byte units)
#define WS_N      0
#define WS_ENT    1
#define WS_CTR    2                    // argmin completion counter (int)
#define WS_CTR2   3                    // update_quant completion counter (int)
#define WS_COUNTS 4                    // 8192 floats (argmin atomics; reused as loss partials)
#define WS_EMB    8196                 // 524288 floats (atomic)
#define WS_IDX    532484               // 32768 ints
#define WS_W2H    565252               // 8192 floats (= ||w||^2 / 2)
#define WS_WFRAG  573444               // 524288 f32 units = 2 MB f16 frag image
#define WS_ZERO_UNITS 532484           // scalars+ctrs+counts+emb

__device__ __forceinline__ float sq_rn(float v) { return __fmul_rn(v, v); }

// numpy pairwise_sum order for 64 contiguous squared values
__device__ __forceinline__ float npsumsq64(const float* vbuf) {
  float a[8];
#pragma unroll
  for (int j = 0; j < 8; ++j) a[j] = sq_rn(vbuf[j]);
#pragma unroll
  for (int m = 1; m < 8; ++m)
#pragma unroll
    for (int j = 0; j < 8; ++j) a[j] = __fadd_rn(a[j], sq_rn(vbuf[m*8 + j]));
  return __fadd_rn(__fadd_rn(__fadd_rn(a[0],a[1]), __fadd_rn(a[2],a[3])),
                   __fadd_rn(__fadd_rn(a[4],a[5]), __fadd_rn(a[6],a[7])));
}

// split a float into (hi, lo) fp16 pair; hi+lo reproduces x to ~22 bits
__device__ __forceinline__ void split_f16(float x, _Float16& hi, _Float16& lo) {
  hi = (_Float16)x;
  float r = __fsub_rn(x, (float)hi);   // exact (Sterbenz)
  lo = (_Float16)r;
}

// prep: grid-stride zero of the atomic regions (replaces hipMemsetAsync),
// w2h[k] = 0.5*||w_k||^2 (numpy order), W -> fragment-image f16 hi/lo.
// Image layout: frag(panel P, s, lane l) at wf[((P*4+s)*64+l)*8 .. +8];
// s=0,1 hi (K 0..31 / 32..63), s=2,3 lo. A per-lane dwordx4 load IS an MFMA frag.
__global__ __launch_bounds__(256) void prep_kernel(const float* __restrict__ wg,
                                                   float* __restrict__ ws) {
  const int tid = blockIdx.x * 256 + threadIdx.x;
  // zero scalars+ctrs+counts+emb (288*256 = 73728 threads, ~7.2 iters)
  for (int z = tid; z < WS_ZERO_UNITS; z += 73728) ws[z] = 0.0f;

  if (tid < KEMB) {
    const float* src = wg + (size_t)tid * 64;
    float vbuf[64];
#pragma unroll
    for (int f = 0; f < 16; ++f) {
      float4 v = *(const float4*)(src + f*4);
      vbuf[f*4+0]=v.x; vbuf[f*4+1]=v.y; vbuf[f*4+2]=v.z; vbuf[f*4+3]=v.w;
    }
    ws[WS_W2H + tid] = __fmul_rn(0.5f, npsumsq64(vbuf));
  } else if (tid < KEMB + 65536) {
    const int u = tid - KEMB;            // granule: code K, dims g*8..g*8+7
    const int K = u >> 3, g = u & 7;
    const int n = K & 15, P = K >> 4;    // global panel 0..511
    const int slot = (g&3)*16 + n, shi = g >> 2;
    const float* src = wg + (size_t)K*64 + g*8;
    float4 v0 = *(const float4*)src, v1 = *(const float4*)(src + 4);
    float vv[8] = {v0.x,v0.y,v0.z,v0.w,v1.x,v1.y,v1.z,v1.w};
    f16x8 hi, lo;
#pragma unroll
    for (int j = 0; j < 8; ++j) { _Float16 h, l; split_f16(vv[j], h, l); hi[j]=h; lo[j]=l; }
    _Float16* wf = (_Float16*)(ws + WS_WFRAG);
    *(f16x8*)&wf[((size_t)(P*4 + shi)*64 + slot)*8]     = hi;
    *(f16x8*)&wf[((size_t)(P*4 + 2 + shi)*64 + slot)*8] = lo;
  }
}

// stream load of one panel into a named register set; pointer advances by
// 2 panels' stride (each set handles every other panel of this wave's slice)
#define LOADP(H0, H1, L0, L1, CW, WP, CP)           \
  H0 = *(const f16x8*)(WP);                         \
  H1 = *(const f16x8*)(WP + 512);                   \
  L0 = *(const f16x8*)(WP + 1024);                  \
  L1 = *(const f16x8*)(WP + 1536);                  \
  CW = *(const f32x4*)(CP);                         \
  WP += 16384; CP += 128;

// tournament, strict-compare form (verified bit-exact in r5/r7/r10)
#define TOURN(ACC, C0)                                                       \
  _Pragma("unroll")                                                          \
  for (int bt = 0; bt < 4; ++bt) {                                           \
    const float d0 = ACC[bt][0], d1 = ACC[bt][1], d2 = ACC[bt][2], d3 = ACC[bt][3]; \
    const float m01 = fminf(d0, d1), m23 = fminf(d2, d3);                    \
    const float pm  = fminf(m01, m23);                                       \
    const int i01 = (d1 < d0) ? 1 : 0;                                       \
    const int i23 = (d3 < d2) ? 3 : 2;                                       \
    const int isel = (m23 < m01) ? i23 : i01;                                \
    if (pm < bestd[bt]) { bestd[bt] = pm; bestk[bt] = (C0) + isel; }         \
  }

// argmin v18: hot loop byte-identical to r10 (98.4us, bit-exact, no spill).
// Ten rounds of microstructure ablation (occupancy, buffering, de-phasing,
// chain count 2..16/SIMD, shape) all null at ~47% MfmaUtil -> this is the
// plain-HIP practical band for this loop family; frozen. NEW: the stats pass
// (new_cc, n, entropy) runs in the LAST block via completion counter,
// eliminating the stats dispatch + one inter-dispatch gap (~10us each).
// Summation order identical to the previously-passing stats_kernel.
__global__ __attribute__((amdgpu_flat_work_group_size(256,256), amdgpu_waves_per_eu(2,2)))
void argmin_kernel(const float* __restrict__ xg,
                   const float* __restrict__ cc,
                   float* __restrict__ out,
                   float* __restrict__ ws) {
  __shared__ __align__(16) _Float16 xp[4*4*64*8];   // 16 KB, X frags (negated)
  __shared__ float md[64*4];
  __shared__ int   mk[64*4];
  __shared__ int   bkL[64];
  __shared__ float s1[4], s2[4];
  __shared__ int   amLast;

  const int t    = threadIdx.x;
  const int lane = t & 63, wv = t >> 6;     // wv 0..3
  const int quad = lane >> 4, n16 = lane & 15;
  const int cg = wv;                        // code slice 0..3
  const int row0 = blockIdx.x * 64;
  const _Float16* __restrict__ wfrag = (const _Float16*)(ws + WS_WFRAG);
  const float* __restrict__ w2hg = ws + WS_W2H;

  // ---- prologue: convert X tile (NEGATED) into fragment layout ----
#pragma unroll
  for (int it = 0; it < 2; ++it) {
    const int u  = t + 256*it;              // < 512 granules (64 rows)
    const int rp = u >> 7, n = (u >> 3) & 15, g = u & 7;
    const float* src = xg + (size_t)(row0 + rp*16 + n)*64 + g*8;
    float4 v0 = *(const float4*)src, v1 = *(const float4*)(src + 4);
    float vv[8] = {v0.x,v0.y,v0.z,v0.w,v1.x,v1.y,v1.z,v1.w};
    f16x8 hi, lo;
#pragma unroll
    for (int j = 0; j < 8; ++j) { _Float16 h, l; split_f16(-vv[j], h, l); hi[j]=h; lo[j]=l; }
    const int slot = (g&3)*16 + n, shi = g >> 2;
    *(f16x8*)&xp[(((rp*4) + shi)*64 + slot)*8]     = hi;
    *(f16x8*)&xp[(((rp*4) + 2 + shi)*64 + slot)*8] = lo;
  }
  __syncthreads();

  // resident X frags (B operand): all 64 rows of this block, 4 tiles of 16
  f16x8 b[4][4];
#pragma unroll
  for (int bt = 0; bt < 4; ++bt)
#pragma unroll
    for (int s = 0; s < 4; ++s)
      b[bt][s] = *(const f16x8*)&xp[(((bt*4) + s)*64 + lane)*8];

  float bestd[4]; int bestk[4];
#pragma unroll
  for (int i = 0; i < 4; ++i) { bestd[i] = INFINITY; bestk[i] = 0; }

  const int q4 = quad * 4;

  // W panel stream: this wave covers panels cg, cg+4, ..., cg+4*127.
  // setA sweeps even-m panels, setB odd-m panels (r5 addressing, unchanged).
  const _Float16* wpA = wfrag + (size_t)cg * 2048 + (size_t)lane * 8;
  const _Float16* wpB = wpA + 8192;
  const float*    cpA = w2hg + cg*16 + q4;
  const float*    cpB = cpA + 64;

  f16x8 hA0, hA1, lA0, lA1, hB0, hB1, lB0, lB1;
  f32x4 cwA, cwB;

  LOADP(hA0, hA1, lA0, lA1, cwA, wpA, cpA);   // panel 0
  LOADP(hB0, hB1, lB0, lB1, cwB, wpB, cpB);   // panel 1

  f32x4 accA[4], accB[4];
  int c0A = cg*16 + q4;                       // even panel codes
  int c0B = c0A + 64;                         // odd panel codes

#pragma unroll 1
  for (int j = 0; j < 64; ++j) {
    // interleaved mega-cluster: panels 2j (A) and 2j+1 (B), 8 chains.
    __builtin_amdgcn_s_setprio(1);
#pragma unroll
    for (int bt = 0; bt < 4; ++bt) accA[bt] = __builtin_amdgcn_mfma_f32_16x16x32_f16(hA0, b[bt][0], cwA,      0,0,0);
#pragma unroll
    for (int bt = 0; bt < 4; ++bt) accB[bt] = __builtin_amdgcn_mfma_f32_16x16x32_f16(hB0, b[bt][0], cwB,      0,0,0);
#pragma unroll
    for (int bt = 0; bt < 4; ++bt) accA[bt] = __builtin_amdgcn_mfma_f32_16x16x32_f16(hA1, b[bt][1], accA[bt], 0,0,0);
#pragma unroll
    for (int bt = 0; bt < 4; ++bt) accB[bt] = __builtin_amdgcn_mfma_f32_16x16x32_f16(hB1, b[bt][1], accB[bt], 0,0,0);
#pragma unroll
    for (int bt = 0; bt < 4; ++bt) accA[bt] = __builtin_amdgcn_mfma_f32_16x16x32_f16(hA0, b[bt][2], accA[bt], 0,0,0);
#pragma unroll
    for (int bt = 0; bt < 4; ++bt) accB[bt] = __builtin_amdgcn_mfma_f32_16x16x32_f16(hB0, b[bt][2], accB[bt], 0,0,0);
#pragma unroll
    for (int bt = 0; bt < 4; ++bt) accA[bt] = __builtin_amdgcn_mfma_f32_16x16x32_f16(hA1, b[bt][3], accA[bt], 0,0,0);
#pragma unroll
    for (int bt = 0; bt < 4; ++bt) accB[bt] = __builtin_amdgcn_mfma_f32_16x16x32_f16(hB1, b[bt][3], accB[bt], 0,0,0);
#pragma unroll
    for (int bt = 0; bt < 4; ++bt) accA[bt] = __builtin_amdgcn_mfma_f32_16x16x32_f16(lA0, b[bt][0], accA[bt], 0,0,0);
#pragma unroll
    for (int bt = 0; bt < 4; ++bt) accB[bt] = __builtin_amdgcn_mfma_f32_16x16x32_f16(lB0, b[bt][0], accB[bt], 0,0,0);
#pragma unroll
    for (int bt = 0; bt < 4; ++bt) accA[bt] = __builtin_amdgcn_mfma_f32_16x16x32_f16(lA1, b[bt][1], accA[bt], 0,0,0);
#pragma unroll
    for (int bt = 0; bt < 4; ++bt) accB[bt] = __builtin_amdgcn_mfma_f32_16x16x32_f16(lB1, b[bt][1], accB[bt], 0,0,0);
    __builtin_amdgcn_s_setprio(0);

    // prefetch next panel pair (WAR-safe: all reads of the sets issued above)
    if (j < 63) {
      LOADP(hA0, hA1, lA0, lA1, cwA, wpA, cpA);   // panel 2j+2
      LOADP(hB0, hB1, lB0, lB1, cwB, wpB, cpB);   // panel 2j+3
    }

    // tournaments: ascending panel order (2j then 2j+1), exact tie semantics
    TOURN(accA, c0A);
    c0A += 128;
    TOURN(accB, c0B);
    c0B += 128;
  }

  // ---- merge across the 4 quads (same row, disjoint code slices) ----
#pragma unroll
  for (int bt = 0; bt < 4; ++bt) {
    float bd = bestd[bt]; int bk = bestk[bt];
#pragma unroll
    for (int m = 16; m < 64; m <<= 1) {
      const float od = __shfl_xor(bd, m, 64);
      const int   ok = __shfl_xor(bk, m, 64);
      if (od < bd || (od == bd && ok < bk)) { bd = od; bk = ok; }
    }
    if (lane < 16) {
      const int row = bt*16 + n16;
      md[row*4 + cg] = bd;
      mk[row*4 + cg] = bk;
    }
  }
  __syncthreads();

  if (t < 64) {
    const int row = t;
    float bd = md[row*4]; int bk = mk[row*4];
#pragma unroll
    for (int u2 = 1; u2 < 4; ++u2) {
      const float d2 = md[row*4 + u2]; const int k2 = mk[row*4 + u2];
      if (d2 < bd || (d2 == bd && k2 < bk)) { bd = d2; bk = k2; }
    }
    out[OUT_IDX + row0 + row] = (float)bk;
    ((int*)ws)[WS_IDX + row0 + row] = bk;
    bkL[row] = bk;
    atomicAdd(&ws[WS_COUNTS + bk], 1.0f);
  }
  __syncthreads();

  // ---- fused EMA segment-sum: 4 waves x 16 rows, lane = dim ----
#pragma unroll 4
  for (int r = 0; r < 16; ++r) {
    const int row = wv*16 + r;
    const int k = bkL[row];
    atomicAdd(&ws[WS_EMB + (size_t)k*64 + lane],
              xg[(size_t)(row0 + row)*64 + lane]);
  }

  // ---- last block runs the stats pass (replaces stats_kernel dispatch) ----
  __threadfence();
  if (t == 0) amLast = (atomicAdd((int*)ws + WS_CTR, 1) == (int)gridDim.x - 1);
  __syncthreads();
  if (amLast) {
    __threadfence();
    float v1 = 0.0f, v2 = 0.0f;
#pragma unroll
    for (int i = 0; i < 32; ++i) {
      const int k = i*256 + t;
      const float cnt = ws[WS_COUNTS + k];
      const float ncc = __fadd_rn(__fmul_rn(DECAYF, cc[k]), __fmul_rn(OMDF, cnt));
      out[OUT_NCC + k] = ncc;
      const float p = cnt * (1.0f/32768.0f);
      v1 += ncc;
      v2 += __fmul_rn(p, logf(__fadd_rn(p, 1e-10f)));
    }
#pragma unroll
    for (int off = 32; off > 0; off >>= 1) {
      v1 += __shfl_down(v1, off);
      v2 += __shfl_down(v2, off);
    }
    if (lane == 0) { s1[wv] = v1; s2[wv] = v2; }
    __syncthreads();
    if (t == 0) {
      ws[WS_N]   = (s1[0]+s1[1]) + (s1[2]+s1[3]);
      ws[WS_ENT] = (s2[0]+s2[1]) + (s2[2]+s2[3]);
    }
  }
}

// fused update + quant + final loss: linear codebook update, gather-quantize
// with on-the-fly recompute of new_weight rows (bit-identical arithmetic),
// last block sums the per-block loss partials (final_kernel's exact order).
__global__ __launch_bounds__(256) void update_quant_kernel(const float* __restrict__ xg,
                                                           const float* __restrict__ ws0,
                                                           float* __restrict__ out,
                                                           float* __restrict__ ws) {
  __shared__ float sm[4];
  __shared__ int amL;
  const int t = threadIdx.x;
  const float n = ws[WS_N];
  const float den = __fadd_rn(n, 0.08192f);

  // ---- linear codebook update: one float4 per thread ----
  const int e4 = blockIdx.x * 256 + t;      // < 131072 float4s
  {
    const int k = e4 >> 4;
    const float ncc = out[OUT_NCC + k];
    const float smoothed = __fmul_rn(__fadd_rn(ncc, 1e-5f) / den, n);
    float4 w0 = *(const float4*)(ws0 + (size_t)e4*4);
    float4 em = *(const float4*)(ws + WS_EMB + (size_t)e4*4);
    float wv4[4] = {w0.x, w0.y, w0.z, w0.w};
    float ev4[4] = {em.x, em.y, em.z, em.w};
    float nwsv[4], nwv[4];
#pragma unroll
    for (int i = 0; i < 4; ++i) {
      nwsv[i] = __fadd_rn(__fmul_rn(DECAYF, wv4[i]), __fmul_rn(OMDF, ev4[i]));
      nwv[i]  = nwsv[i] / smoothed;         // exact division (reference: nws / smoothed)
    }
    float4 onws = {nwsv[0], nwsv[1], nwsv[2], nwsv[3]};
    float4 onw  = {nwv[0],  nwv[1],  nwv[2],  nwv[3]};
    *(float4*)(out + OUT_NWS + (size_t)e4*4) = onws;
    *(float4*)(out + OUT_NW  + (size_t)e4*4) = onw;
    if (e4 == 0) out[OUT_PERP] = expf(-ws[WS_ENT]);
  }

  // ---- quant + loss partials (per-block slot in WS_COUNTS, post-stats reuse) ----
  const int* idxb = (const int*)ws + WS_IDX;
  float v = 0.0f;
#pragma unroll
  for (int j = 0; j < 4; ++j) {
    const int qe4 = (j*512 + blockIdx.x)*256 + t;   // float4 index, coalesced
    const int row = qe4 >> 4, d = (qe4 & 15) * 4;
    const int k = idxb[row];
    const float ncc = out[OUT_NCC + k];
    const float smK = __fmul_rn(__fadd_rn(ncc, 1e-5f) / den, n);
    float4 wq = *(const float4*)(ws0 + (size_t)k*64 + d);
    float4 eq = *(const float4*)(ws + WS_EMB + (size_t)k*64 + d);
    float4 x  = *(const float4*)(xg + (size_t)qe4*4);
    float wv4[4] = {wq.x,wq.y,wq.z,wq.w};
    float ev4[4] = {eq.x,eq.y,eq.z,eq.w};
    float xv[4]  = {x.x,x.y,x.z,x.w};
    float4 o; float ov[4];
#pragma unroll
    for (int i = 0; i < 4; ++i) {
      const float nws = __fadd_rn(__fmul_rn(DECAYF, wv4[i]), __fmul_rn(OMDF, ev4[i]));
      const float q = nws / smK;            // == new_weight[k][d+i], identical rounding
      const float df = __fsub_rn(q, xv[i]);
      ov[i] = __fadd_rn(xv[i], df);
      v = fmaf(df, df, v);
    }
    o.x = ov[0]; o.y = ov[1]; o.z = ov[2]; o.w = ov[3];
    *(float4*)(out + OUT_Q + (size_t)qe4*4) = o;
  }
#pragma unroll
  for (int off = 32; off > 0; off >>= 1) v += __shfl_down(v, off);
  const int lane = t & 63, wid = t >> 6;
  if (lane == 0) sm[wid] = v;
  __syncthreads();
  if (t == 0) ws[WS_COUNTS + blockIdx.x] = (sm[0]+sm[1]) + (sm[2]+sm[3]);

  // ---- last block computes final loss (replaces final_kernel dispatch) ----
  __threadfence();
  if (t == 0) amL = (atomicAdd((int*)ws + WS_CTR2, 1) == (int)gridDim.x - 1);
  __syncthreads();
  if (amL) {
    __threadfence();
    if (t < 64) {
      float vv = 0.0f;
#pragma unroll
      for (int i = 0; i < 8; ++i) vv += ws[WS_COUNTS + i*64 + t];
#pragma unroll
      for (int off = 32; off > 0; off >>= 1) vv += __shfl_down(vv, off);
      if (t == 0) out[OUT_LOSS] = __fmul_rn(0.25f, vv / 2097152.0f);
    }
  }
}

extern "C" void kernel_launch(void* const* d_in, const int* in_sizes, int n_in,
                              void* d_out, int out_size, void* d_ws, size_t ws_size,
                              hipStream_t stream) {
  (void)in_sizes; (void)n_in; (void)out_size; (void)ws_size;
  const float* x   = (const float*)d_in[0];
  const float* w   = (const float*)d_in[1];
  const float* cc  = (const float*)d_in[2];
  const float* ws0 = (const float*)d_in[3];
  float* out = (float*)d_out;
  float* ws  = (float*)d_ws;

  hipLaunchKernelGGL(prep_kernel,         dim3(288), dim3(256), 0, stream, w, ws);
  hipLaunchKernelGGL(argmin_kernel,       dim3(512), dim3(256), 0, stream, x, cc, out, ws);
  hipLaunchKernelGGL(update_quant_kernel, dim3(512), dim3(256), 0, stream, x, ws0, out, ws);
}

// Round 12
// 172.974 us; speedup vs baseline: 1.4513x; 1.4513x over previous
//
#include <hip/hip_runtime.h>
#include <math.h>

typedef _Float16 f16x8 __attribute__((ext_vector_type(8)));
typedef float f32x4 __attribute__((ext_vector_type(4)));

// Problem constants
#define NROWS 32768   // 8*4096 input rows
#define KEMB  8192    // codebook entries
// DIM = 64

#define DECAYF 0.99f
#define OMDF   0.01f

// d_out layout (floats), reference return order
#define OUT_Q    0          // quantized, 2097152
#define OUT_LOSS 2097152    // vq_loss, 1
#define OUT_IDX  2097153    // idx (as float), 32768
#define OUT_PERP 2129921    // perplexity, 1
#define OUT_NW   2129922    // new_weight, 524288
#define OUT_NCC  2654210    // new_cc, 8192
#define OUT_NWS  2662402    // new_ws, 524288

// d_ws layout (4-byte units)
#define WS_N      0
#define WS_ENT    1
#define WS_COUNTS 4                    // 8192 floats (argmin count atomics; read-only afterwards)
#define WS_EMB    8196                 // 524288 floats (atomic)
#define WS_IDX    532484               // 32768 ints
#define WS_W2H    565252               // 8192 floats (= ||w||^2/2; reused as loss partials post-argmin)
#define WS_WFRAG  573444               // 524288 f32 units = 2 MB f16 frag image
#define WS_ZERO_UNITS 532484           // scalars+counts+emb

__device__ __forceinline__ float sq_rn(float v) { return __fmul_rn(v, v); }

// numpy pairwise_sum order for 64 contiguous squared values
__device__ __forceinline__ float npsumsq64(const float* vbuf) {
  float a[8];
#pragma unroll
  for (int j = 0; j < 8; ++j) a[j] = sq_rn(vbuf[j]);
#pragma unroll
  for (int m = 1; m < 8; ++m)
#pragma unroll
    for (int j = 0; j < 8; ++j) a[j] = __fadd_rn(a[j], sq_rn(vbuf[m*8 + j]));
  return __fadd_rn(__fadd_rn(__fadd_rn(a[0],a[1]), __fadd_rn(a[2],a[3])),
                   __fadd_rn(__fadd_rn(a[4],a[5]), __fadd_rn(a[6],a[7])));
}

// split a float into (hi, lo) fp16 pair; hi+lo reproduces x to ~22 bits
__device__ __forceinline__ void split_f16(float x, _Float16& hi, _Float16& lo) {
  hi = (_Float16)x;
  float r = __fsub_rn(x, (float)hi);   // exact (Sterbenz)
  lo = (_Float16)r;
}

// prep: grid-stride zero of the atomic regions (replaces hipMemsetAsync),
// w2h[k] = 0.5*||w_k||^2 (numpy order), W -> fragment-image f16 hi/lo.
// Image layout: frag(panel P, s, lane l) at wf[((P*4+s)*64+l)*8 .. +8];
// s=0,1 hi (K 0..31 / 32..63), s=2,3 lo. A per-lane dwordx4 load IS an MFMA frag.
__global__ __launch_bounds__(256) void prep_kernel(const float* __restrict__ wg,
                                                   float* __restrict__ ws) {
  const int tid = blockIdx.x * 256 + threadIdx.x;
  // zero scalars+counts+emb (288*256 = 73728 threads, ~7.2 iters, coalesced)
  for (int z = tid; z < WS_ZERO_UNITS; z += 73728) ws[z] = 0.0f;

  if (tid < KEMB) {
    const float* src = wg + (size_t)tid * 64;
    float vbuf[64];
#pragma unroll
    for (int f = 0; f < 16; ++f) {
      float4 v = *(const float4*)(src + f*4);
      vbuf[f*4+0]=v.x; vbuf[f*4+1]=v.y; vbuf[f*4+2]=v.z; vbuf[f*4+3]=v.w;
    }
    ws[WS_W2H + tid] = __fmul_rn(0.5f, npsumsq64(vbuf));
  } else if (tid < KEMB + 65536) {
    const int u = tid - KEMB;            // granule: code K, dims g*8..g*8+7
    const int K = u >> 3, g = u & 7;
    const int n = K & 15, P = K >> 4;    // global panel 0..511
    const int slot = (g&3)*16 + n, shi = g >> 2;
    const float* src = wg + (size_t)K*64 + g*8;
    float4 v0 = *(const float4*)src, v1 = *(const float4*)(src + 4);
    float vv[8] = {v0.x,v0.y,v0.z,v0.w,v1.x,v1.y,v1.z,v1.w};
    f16x8 hi, lo;
#pragma unroll
    for (int j = 0; j < 8; ++j) { _Float16 h, l; split_f16(vv[j], h, l); hi[j]=h; lo[j]=l; }
    _Float16* wf = (_Float16*)(ws + WS_WFRAG);
    *(f16x8*)&wf[((size_t)(P*4 + shi)*64 + slot)*8]     = hi;
    *(f16x8*)&wf[((size_t)(P*4 + 2 + shi)*64 + slot)*8] = lo;
  }
}

// stream load of one panel into a named register set; pointer advances by
// 2 panels' stride (each set handles every other panel of this wave's slice)
#define LOADP(H0, H1, L0, L1, CW, WP, CP)           \
  H0 = *(const f16x8*)(WP);                         \
  H1 = *(const f16x8*)(WP + 512);                   \
  L0 = *(const f16x8*)(WP + 1024);                  \
  L1 = *(const f16x8*)(WP + 1536);                  \
  CW = *(const f32x4*)(CP);                         \
  WP += 16384; CP += 128;

// tournament, strict-compare form (verified bit-exact in r5/r7/r10)
#define TOURN(ACC, C0)                                                       \
  _Pragma("unroll")                                                          \
  for (int bt = 0; bt < 4; ++bt) {                                           \
    const float d0 = ACC[bt][0], d1 = ACC[bt][1], d2 = ACC[bt][2], d3 = ACC[bt][3]; \
    const float m01 = fminf(d0, d1), m23 = fminf(d2, d3);                    \
    const float pm  = fminf(m01, m23);                                       \
    const int i01 = (d1 < d0) ? 1 : 0;                                       \
    const int i23 = (d3 < d2) ? 3 : 2;                                       \
    const int isel = (m23 < m01) ? i23 : i01;                                \
    if (pm < bestd[bt]) { bestd[bt] = pm; bestk[bt] = (C0) + isel; }         \
  }

// argmin v19 = r10's kernel byte-for-byte (98.4us, bit-exact, no spill).
// r11's last-block stats fusion added __threadfence (device-scope L2
// writeback/inv) in all 2048 waves -> +32us tail; reverted. Inter-kernel
// deps stay at dispatch boundaries (runtime-flushed, fence-free).
__global__ __attribute__((amdgpu_flat_work_group_size(256,256), amdgpu_waves_per_eu(2,2)))
void argmin_kernel(const float* __restrict__ xg,
                   float* __restrict__ out,
                   float* __restrict__ ws) {
  __shared__ __align__(16) _Float16 xp[4*4*64*8];   // 16 KB, X frags (negated)
  __shared__ float md[64*4];
  __shared__ int   mk[64*4];
  __shared__ int   bkL[64];

  const int t    = threadIdx.x;
  const int lane = t & 63, wv = t >> 6;     // wv 0..3
  const int quad = lane >> 4, n16 = lane & 15;
  const int cg = wv;                        // code slice 0..3
  const int row0 = blockIdx.x * 64;
  const _Float16* __restrict__ wfrag = (const _Float16*)(ws + WS_WFRAG);
  const float* __restrict__ w2hg = ws + WS_W2H;

  // ---- prologue: convert X tile (NEGATED) into fragment layout ----
#pragma unroll
  for (int it = 0; it < 2; ++it) {
    const int u  = t + 256*it;              // < 512 granules (64 rows)
    const int rp = u >> 7, n = (u >> 3) & 15, g = u & 7;
    const float* src = xg + (size_t)(row0 + rp*16 + n)*64 + g*8;
    float4 v0 = *(const float4*)src, v1 = *(const float4*)(src + 4);
    float vv[8] = {v0.x,v0.y,v0.z,v0.w,v1.x,v1.y,v1.z,v1.w};
    f16x8 hi, lo;
#pragma unroll
    for (int j = 0; j < 8; ++j) { _Float16 h, l; split_f16(-vv[j], h, l); hi[j]=h; lo[j]=l; }
    const int slot = (g&3)*16 + n, shi = g >> 2;
    *(f16x8*)&xp[(((rp*4) + shi)*64 + slot)*8]     = hi;
    *(f16x8*)&xp[(((rp*4) + 2 + shi)*64 + slot)*8] = lo;
  }
  __syncthreads();

  // resident X frags (B operand): all 64 rows of this block, 4 tiles of 16
  f16x8 b[4][4];
#pragma unroll
  for (int bt = 0; bt < 4; ++bt)
#pragma unroll
    for (int s = 0; s < 4; ++s)
      b[bt][s] = *(const f16x8*)&xp[(((bt*4) + s)*64 + lane)*8];

  float bestd[4]; int bestk[4];
#pragma unroll
  for (int i = 0; i < 4; ++i) { bestd[i] = INFINITY; bestk[i] = 0; }

  const int q4 = quad * 4;

  // W panel stream: this wave covers panels cg, cg+4, ..., cg+4*127.
  // setA sweeps even-m panels, setB odd-m panels (r5 addressing, unchanged).
  const _Float16* wpA = wfrag + (size_t)cg * 2048 + (size_t)lane * 8;
  const _Float16* wpB = wpA + 8192;
  const float*    cpA = w2hg + cg*16 + q4;
  const float*    cpB = cpA + 64;

  f16x8 hA0, hA1, lA0, lA1, hB0, hB1, lB0, lB1;
  f32x4 cwA, cwB;

  LOADP(hA0, hA1, lA0, lA1, cwA, wpA, cpA);   // panel 0
  LOADP(hB0, hB1, lB0, lB1, cwB, wpB, cpB);   // panel 1

  f32x4 accA[4], accB[4];
  int c0A = cg*16 + q4;                       // even panel codes
  int c0B = c0A + 64;                         // odd panel codes

#pragma unroll 1
  for (int j = 0; j < 64; ++j) {
    // interleaved mega-cluster: panels 2j (A) and 2j+1 (B), 8 chains.
    __builtin_amdgcn_s_setprio(1);
#pragma unroll
    for (int bt = 0; bt < 4; ++bt) accA[bt] = __builtin_amdgcn_mfma_f32_16x16x32_f16(hA0, b[bt][0], cwA,      0,0,0);
#pragma unroll
    for (int bt = 0; bt < 4; ++bt) accB[bt] = __builtin_amdgcn_mfma_f32_16x16x32_f16(hB0, b[bt][0], cwB,      0,0,0);
#pragma unroll
    for (int bt = 0; bt < 4; ++bt) accA[bt] = __builtin_amdgcn_mfma_f32_16x16x32_f16(hA1, b[bt][1], accA[bt], 0,0,0);
#pragma unroll
    for (int bt = 0; bt < 4; ++bt) accB[bt] = __builtin_amdgcn_mfma_f32_16x16x32_f16(hB1, b[bt][1], accB[bt], 0,0,0);
#pragma unroll
    for (int bt = 0; bt < 4; ++bt) accA[bt] = __builtin_amdgcn_mfma_f32_16x16x32_f16(hA0, b[bt][2], accA[bt], 0,0,0);
#pragma unroll
    for (int bt = 0; bt < 4; ++bt) accB[bt] = __builtin_amdgcn_mfma_f32_16x16x32_f16(hB0, b[bt][2], accB[bt], 0,0,0);
#pragma unroll
    for (int bt = 0; bt < 4; ++bt) accA[bt] = __builtin_amdgcn_mfma_f32_16x16x32_f16(hA1, b[bt][3], accA[bt], 0,0,0);
#pragma unroll
    for (int bt = 0; bt < 4; ++bt) accB[bt] = __builtin_amdgcn_mfma_f32_16x16x32_f16(hB1, b[bt][3], accB[bt], 0,0,0);
#pragma unroll
    for (int bt = 0; bt < 4; ++bt) accA[bt] = __builtin_amdgcn_mfma_f32_16x16x32_f16(lA0, b[bt][0], accA[bt], 0,0,0);
#pragma unroll
    for (int bt = 0; bt < 4; ++bt) accB[bt] = __builtin_amdgcn_mfma_f32_16x16x32_f16(lB0, b[bt][0], accB[bt], 0,0,0);
#pragma unroll
    for (int bt = 0; bt < 4; ++bt) accA[bt] = __builtin_amdgcn_mfma_f32_16x16x32_f16(lA1, b[bt][1], accA[bt], 0,0,0);
#pragma unroll
    for (int bt = 0; bt < 4; ++bt) accB[bt] = __builtin_amdgcn_mfma_f32_16x16x32_f16(lB1, b[bt][1], accB[bt], 0,0,0);
    __builtin_amdgcn_s_setprio(0);

    // prefetch next panel pair (WAR-safe: all reads of the sets issued above)
    if (j < 63) {
      LOADP(hA0, hA1, lA0, lA1, cwA, wpA, cpA);   // panel 2j+2
      LOADP(hB0, hB1, lB0, lB1, cwB, wpB, cpB);   // panel 2j+3
    }

    // tournaments: ascending panel order (2j then 2j+1), exact tie semantics
    TOURN(accA, c0A);
    c0A += 128;
    TOURN(accB, c0B);
    c0B += 128;
  }

  // ---- merge across the 4 quads (same row, disjoint code slices) ----
#pragma unroll
  for (int bt = 0; bt < 4; ++bt) {
    float bd = bestd[bt]; int bk = bestk[bt];
#pragma unroll
    for (int m = 16; m < 64; m <<= 1) {
      const float od = __shfl_xor(bd, m, 64);
      const int   ok = __shfl_xor(bk, m, 64);
      if (od < bd || (od == bd && ok < bk)) { bd = od; bk = ok; }
    }
    if (lane < 16) {
      const int row = bt*16 + n16;
      md[row*4 + cg] = bd;
      mk[row*4 + cg] = bk;
    }
  }
  __syncthreads();

  if (t < 64) {
    const int row = t;
    float bd = md[row*4]; int bk = mk[row*4];
#pragma unroll
    for (int u2 = 1; u2 < 4; ++u2) {
      const float d2 = md[row*4 + u2]; const int k2 = mk[row*4 + u2];
      if (d2 < bd || (d2 == bd && k2 < bk)) { bd = d2; bk = k2; }
    }
    out[OUT_IDX + row0 + row] = (float)bk;
    ((int*)ws)[WS_IDX + row0 + row] = bk;
    bkL[row] = bk;
    atomicAdd(&ws[WS_COUNTS + bk], 1.0f);
  }
  __syncthreads();

  // ---- fused EMA segment-sum: 4 waves x 16 rows, lane = dim ----
#pragma unroll 4
  for (int r = 0; r < 16; ++r) {
    const int row = wv*16 + r;
    const int k = bkL[row];
    atomicAdd(&ws[WS_EMB + (size_t)k*64 + lane],
              xg[(size_t)(row0 + row)*64 + lane]);
  }
}

// update_quant v2: fence-free stats fusion. Every block recomputes n from
// WS_COUNTS + cc in the stats_kernel's exact summation order (deterministic
// -> bit-identical n in all blocks; ~0.5us, 64KB L2-resident). Block 0 also
// computes entropy and writes OUT_NCC / OUT_PERP. ncc is recomputed wherever
// needed (same 2 rounding ops -> identical bits). No intra-dispatch deps,
// no fences. Loss partials go to WS_W2H (dead after argmin) since WS_COUNTS
// must stay readable throughout.
__global__ __launch_bounds__(256) void update_quant_kernel(const float* __restrict__ xg,
                                                           const float* __restrict__ ws0,
                                                           const float* __restrict__ cc,
                                                           float* __restrict__ out,
                                                           float* __restrict__ ws) {
  __shared__ float s1[4], s2[4];
  __shared__ float sm[4];
  const int t = threadIdx.x;
  const int lane = t & 63, wid = t >> 6;

  // ---- replicated stats: n (all blocks); entropy + NCC writes (block 0) ----
  float v1 = 0.0f, v2 = 0.0f;
  if (blockIdx.x == 0) {
#pragma unroll
    for (int i = 0; i < 32; ++i) {
      const int k = i*256 + t;
      const float cnt = ws[WS_COUNTS + k];
      const float ncc = __fadd_rn(__fmul_rn(DECAYF, cc[k]), __fmul_rn(OMDF, cnt));
      out[OUT_NCC + k] = ncc;
      const float p = cnt * (1.0f/32768.0f);
      v1 += ncc;
      v2 += __fmul_rn(p, logf(__fadd_rn(p, 1e-10f)));
    }
  } else {
#pragma unroll
    for (int i = 0; i < 32; ++i) {
      const int k = i*256 + t;
      const float cnt = ws[WS_COUNTS + k];
      const float ncc = __fadd_rn(__fmul_rn(DECAYF, cc[k]), __fmul_rn(OMDF, cnt));
      v1 += ncc;
    }
  }
#pragma unroll
  for (int off = 32; off > 0; off >>= 1) {
    v1 += __shfl_down(v1, off);
    v2 += __shfl_down(v2, off);
  }
  if (lane == 0) { s1[wid] = v1; s2[wid] = v2; }
  __syncthreads();
  const float n = (s1[0]+s1[1]) + (s1[2]+s1[3]);          // bit-identical in every block
  if (blockIdx.x == 0 && t == 0)
    out[OUT_PERP] = expf(-((s2[0]+s2[1]) + (s2[2]+s2[3])));
  const float den = __fadd_rn(n, 0.08192f);
  __syncthreads();   // s1/s2 reuse barrier (sm aliasing safety)

  // ---- linear codebook update: one float4 per thread ----
  const int e4 = blockIdx.x * 256 + t;      // < 131072 float4s
  {
    const int k = e4 >> 4;
    const float cnt = ws[WS_COUNTS + k];
    const float ncc = __fadd_rn(__fmul_rn(DECAYF, cc[k]), __fmul_rn(OMDF, cnt));
    const float smoothed = __fmul_rn(__fadd_rn(ncc, 1e-5f) / den, n);
    float4 w0 = *(const float4*)(ws0 + (size_t)e4*4);
    float4 em = *(const float4*)(ws + WS_EMB + (size_t)e4*4);
    float wv4[4] = {w0.x, w0.y, w0.z, w0.w};
    float ev4[4] = {em.x, em.y, em.z, em.w};
    float nwsv[4], nwv[4];
#pragma unroll
    for (int i = 0; i < 4; ++i) {
      nwsv[i] = __fadd_rn(__fmul_rn(DECAYF, wv4[i]), __fmul_rn(OMDF, ev4[i]));
      nwv[i]  = nwsv[i] / smoothed;         // exact division (reference: nws / smoothed)
    }
    float4 onws = {nwsv[0], nwsv[1], nwsv[2], nwsv[3]};
    float4 onw  = {nwv[0],  nwv[1],  nwv[2],  nwv[3]};
    *(float4*)(out + OUT_NWS + (size_t)e4*4) = onws;
    *(float4*)(out + OUT_NW  + (size_t)e4*4) = onw;
  }

  // ---- quant + loss partials (per-block slot in WS_W2H) ----
  const int* idxb = (const int*)ws + WS_IDX;
  float v = 0.0f;
#pragma unroll
  for (int j = 0; j < 4; ++j) {
    const int qe4 = (j*512 + blockIdx.x)*256 + t;   // float4 index, coalesced
    const int row = qe4 >> 4, d = (qe4 & 15) * 4;
    const int k = idxb[row];
    const float ncc = __fadd_rn(__fmul_rn(DECAYF, cc[k]), __fmul_rn(OMDF, ws[WS_COUNTS + k]));
    const float smK = __fmul_rn(__fadd_rn(ncc, 1e-5f) / den, n);
    float4 wq = *(const float4*)(ws0 + (size_t)k*64 + d);
    float4 eq = *(const float4*)(ws + WS_EMB + (size_t)k*64 + d);
    float4 x  = *(const float4*)(xg + (size_t)qe4*4);
    float wv4[4] = {wq.x,wq.y,wq.z,wq.w};
    float ev4[4] = {eq.x,eq.y,eq.z,eq.w};
    float xv[4]  = {x.x,x.y,x.z,x.w};
    float4 o; float ov[4];
#pragma unroll
    for (int i = 0; i < 4; ++i) {
      const float nws = __fadd_rn(__fmul_rn(DECAYF, wv4[i]), __fmul_rn(OMDF, ev4[i]));
      const float q = nws / smK;            // == new_weight[k][d+i], identical rounding
      const float df = __fsub_rn(q, xv[i]);
      ov[i] = __fadd_rn(xv[i], df);
      v = fmaf(df, df, v);
    }
    o.x = ov[0]; o.y = ov[1]; o.z = ov[2]; o.w = ov[3];
    *(float4*)(out + OUT_Q + (size_t)qe4*4) = o;
  }
#pragma unroll
  for (int off = 32; off > 0; off >>= 1) v += __shfl_down(v, off);
  if (lane == 0) sm[wid] = v;
  __syncthreads();
  if (t == 0) ws[WS_W2H + blockIdx.x] = (sm[0]+sm[1]) + (sm[2]+sm[3]);
}

__global__ void final_kernel(float* __restrict__ out, const float* __restrict__ ws) {
  const int t = threadIdx.x;   // 64 threads
  float v = 0.0f;
#pragma unroll
  for (int i = 0; i < 8; ++i) v += ws[WS_W2H + i*64 + t];
#pragma unroll
  for (int off = 32; off > 0; off >>= 1) v += __shfl_down(v, off);
  if (t == 0) out[OUT_LOSS] = __fmul_rn(0.25f, v / 2097152.0f);
}

extern "C" void kernel_launch(void* const* d_in, const int* in_sizes, int n_in,
                              void* d_out, int out_size, void* d_ws, size_t ws_size,
                              hipStream_t stream) {
  (void)in_sizes; (void)n_in; (void)out_size; (void)ws_size;
  const float* x   = (const float*)d_in[0];
  const float* w   = (const float*)d_in[1];
  const float* cc  = (const float*)d_in[2];
  const float* ws0 = (const float*)d_in[3];
  float* out = (float*)d_out;
  float* ws  = (float*)d_ws;

  hipLaunchKernelGGL(prep_kernel,         dim3(288), dim3(256), 0, stream, w, ws);
  hipLaunchKernelGGL(argmin_kernel,       dim3(512), dim3(256), 0, stream, x, out, ws);
  hipLaunchKernelGGL(update_quant_kernel, dim3(512), dim3(256), 0, stream, x, ws0, cc, out, ws);
  hipLaunchKernelGGL(final_kernel,        dim3(1),   dim3(64),  0, stream, out, ws);
}